// Round 3
// baseline (5306.216 us; speedup 1.0000x reference)
//
#include <hip/hip_runtime.h>
#include <hip/hip_bf16.h>
#include <cstdint>
#include <cstddef>

// Model: B=1024, S=60, CIN=25, D=256, H=256, T=S+2=62
// Inputs fp32, output fp32 (reference dtypes); harness permits bf16 compute
// (2% absmax threshold). Internal: activations bf16, accum fp32.
//
//   f2b_kernel  : Wih0/Whh0/Wih1/Whh1 fp32 -> bf16 [ws]
//   embed_kernel: x -> seq (62,1024,256) bf16      [ws]
//   lstm_kernel<256>: seq -> h0 (62,1024,512) bf16 [ws]
//   lstm_kernel<512>: h0  -> h1 (62,1024,512) bf16 [ws]
//   lout_kernel : h1[1..60] @ Wlp^T -> out[...,0:6]   (fp32)
//   gout_kernel : [h1[0],h1[61]] @ Wgp^T -> out[...,6:14] (fp32)
//
// lstm_kernel: persistent, 128 WGs = 64 batch-tiles(16) x 2 dirs, 256 thr (4 waves).
// Wave w owns hidden units [64w,64w+64). All 4 gates of a unit land in the same
// lane's accumulators -> in-register cell update; h broadcast via LDS (bf16),
// c state in fp32 registers.

typedef __attribute__((ext_vector_type(8))) short short8;
typedef __attribute__((ext_vector_type(4))) float floatx4;

#define BATCH 1024
#define TSTEPS 62

__device__ __forceinline__ float bf2f(short s) {
    union { unsigned u; float f; } v;
    v.u = ((unsigned)(unsigned short)s) << 16;
    return v.f;
}
__device__ __forceinline__ short f2bf(float f) {
    union { float f; unsigned u; } v; v.f = f;
    unsigned r = (v.u + 0x7fffu + ((v.u >> 16) & 1u)) >> 16;  // RNE
    return (short)r;
}
__device__ __forceinline__ float sigf(float x) { return 1.0f / (1.0f + __expf(-x)); }

// ---------------- fp32 -> bf16 weight conversion ---------------------------
__global__ __launch_bounds__(256) void f2b_kernel(
    const float* __restrict__ src, short* __restrict__ dst, int n)
{
    int i = blockIdx.x * 256 + threadIdx.x;
    if (i < n) dst[i] = f2bf(src[i]);
}

// ---------------- embed: seq[t][b][d] --------------------------------------
__global__ __launch_bounds__(256) void embed_kernel(
    const float* __restrict__ x, const float* __restrict__ Wg,
    const float* __restrict__ bg, const float* __restrict__ Wl,
    const float* __restrict__ bl, short* __restrict__ seq)
{
    const int b = blockIdx.x;
    const int d = threadIdx.x;  // 256 = D
    __shared__ float xs[1500];  // x[b] : 60*25 fp32
    for (int i = d; i < 1500; i += 256) xs[i] = x[(size_t)b * 1500 + i];
    __syncthreads();

    float g = bg[d];
#pragma unroll
    for (int c = 0; c < 16; ++c) g += xs[9 + c] * Wg[d * 16 + c];
    short gb = f2bf(g);
    seq[((size_t)0 * BATCH + b) * 256 + d] = gb;
    seq[((size_t)61 * BATCH + b) * 256 + d] = gb;

    for (int t = 0; t < 60; ++t) {
        float v = bl[d];
#pragma unroll
        for (int c = 0; c < 9; ++c) v += xs[t * 25 + c] * Wl[d * 9 + c];
        seq[((size_t)(t + 1) * BATCH + b) * 256 + d] = f2bf(v);
    }
}

// ---------------- persistent biLSTM layer ----------------------------------
template <int XS>  // input width: 256 (layer0) or 512 (layer1)
__global__ __launch_bounds__(256, 1) void lstm_kernel(
    const short* __restrict__ X,      // (62, 1024, XS) bf16, time-major
    const short* __restrict__ Wih,    // (2, 1024, XS) bf16 (pre-converted)
    const short* __restrict__ Whh,    // (2, 1024, 256) bf16
    const float* __restrict__ bih,    // (2, 1024) fp32
    const float* __restrict__ bhh,    // (2, 1024) fp32
    short* __restrict__ Hout)         // (62, 1024, 512); dir d -> cols [256d,256d+256)
{
    const int wg    = blockIdx.x;     // 128 = 64 tiles x 2 dirs
    const int dir   = wg >> 6;
    const int bbase = (wg & 63) * 16;
    const int tid   = threadIdx.x;
    const int wv    = tid >> 6;       // wave 0..3 -> hidden units [64w,64w+64)
    const int lane  = tid & 63;
    const int quad  = lane >> 4;      // C rows quad*4..quad*4+3 ; A/B k-offset quad*8
    const int lr    = lane & 15;      // A row (batch) / B row (gate col) / C col

    __shared__ __align__(16) short h_lds[16][264];  // +8 pad

    for (int i = tid; i < 16 * 264; i += 256) (&h_lds[0][0])[i] = 0;

    const short* WihD = Wih + (size_t)dir * 1024 * XS;
    const short* WhhD = Whh + (size_t)dir * 1024 * 256;

    float bias_v[4][4];
#pragma unroll
    for (int g = 0; g < 4; ++g)
#pragma unroll
        for (int s = 0; s < 4; ++s) {
            int col = g * 256 + wv * 64 + s * 16 + lr;
            bias_v[g][s] = bih[dir * 1024 + col] + bhh[dir * 1024 + col];
        }
    float c_st[4][4];  // [sub s][reg r] ; (m = quad*4+r, j = wv*64+s*16+lr)
#pragma unroll
    for (int s = 0; s < 4; ++s)
#pragma unroll
        for (int r = 0; r < 4; ++r) c_st[s][r] = 0.0f;

    __syncthreads();

    for (int st = 0; st < TSTEPS; ++st) {
        const int t = dir ? (TSTEPS - 1 - st) : st;

        floatx4 acc[4][4];
#pragma unroll
        for (int g = 0; g < 4; ++g)
#pragma unroll
            for (int s = 0; s < 4; ++s) {
                float bv = bias_v[g][s];
                acc[g][s] = (floatx4){bv, bv, bv, bv};
            }

        // ---- input contribution: A = X[t] rows (16 batch rows), B = Wih ----
        const short* Xrow = X + ((size_t)t * BATCH + bbase + lr) * XS + quad * 8;
#pragma unroll 2
        for (int kb = 0; kb < XS / 32; ++kb) {
            short8 a = *reinterpret_cast<const short8*>(Xrow + kb * 32);
#pragma unroll
            for (int g = 0; g < 4; ++g) {
#pragma unroll
                for (int s = 0; s < 4; ++s) {
                    const short* bp = WihD + (size_t)g * (256 * XS) +
                                      (wv * 64 + s * 16 + lr) * XS + kb * 32 + quad * 8;
                    short8 b = *reinterpret_cast<const short8*>(bp);
                    acc[g][s] = __builtin_amdgcn_mfma_f32_16x16x32_bf16(a, b, acc[g][s], 0, 0, 0);
                }
            }
        }
        // ---- recurrent contribution: A = h (LDS), B = Whh ----
#pragma unroll 2
        for (int kb = 0; kb < 8; ++kb) {
            short8 a = *reinterpret_cast<const short8*>(&h_lds[lr][kb * 32 + quad * 8]);
#pragma unroll
            for (int g = 0; g < 4; ++g) {
#pragma unroll
                for (int s = 0; s < 4; ++s) {
                    const short* bp = WhhD + (size_t)g * (256 * 256) +
                                      (wv * 64 + s * 16 + lr) * 256 + kb * 32 + quad * 8;
                    short8 b = *reinterpret_cast<const short8*>(bp);
                    acc[g][s] = __builtin_amdgcn_mfma_f32_16x16x32_bf16(a, b, acc[g][s], 0, 0, 0);
                }
            }
        }

        __syncthreads();  // everyone done reading h_lds

        // ---- cell update, in-register (i,f,g,o co-located per lane) ----
#pragma unroll
        for (int s = 0; s < 4; ++s) {
#pragma unroll
            for (int r = 0; r < 4; ++r) {
                float iv = acc[0][s][r], fv = acc[1][s][r];
                float gv = acc[2][s][r], ov = acc[3][s][r];
                float c = sigf(fv) * c_st[s][r] + sigf(iv) * tanhf(gv);
                c_st[s][r] = c;
                float h = sigf(ov) * tanhf(c);
                short hb = f2bf(h);
                int m = quad * 4 + r;
                int j = wv * 64 + s * 16 + lr;
                h_lds[m][j] = hb;
                Hout[((size_t)t * BATCH + bbase + m) * 512 + dir * 256 + j] = hb;
            }
        }
        __syncthreads();  // new h visible before next step's reads
    }
}

// ---------------- heads (fp32 output) --------------------------------------
// one thread per (b,s): stream the 512-wide h row once, 6 fp32 dots
__global__ __launch_bounds__(256) void lout_kernel(
    const short* __restrict__ h1, const float* __restrict__ Wlp,
    const float* __restrict__ blp, float* __restrict__ out)
{
    __shared__ float wl[6 * 512];
    for (int i = threadIdx.x; i < 6 * 512; i += 256) wl[i] = Wlp[i];
    __syncthreads();

    int idx = blockIdx.x * 256 + threadIdx.x;
    if (idx >= BATCH * 60) return;
    int b = idx & (BATCH - 1);
    int s = idx >> 10;  // 0..59
    const short* hrow = h1 + ((size_t)(s + 1) * BATCH + b) * 512;

    float acc[6];
#pragma unroll
    for (int j = 0; j < 6; ++j) acc[j] = blp[j];
    for (int k = 0; k < 512; k += 8) {
        short8 hv = *reinterpret_cast<const short8*>(hrow + k);
#pragma unroll
        for (int e = 0; e < 8; ++e) {
            float h = bf2f(hv[e]);
#pragma unroll
            for (int j = 0; j < 6; ++j) acc[j] += h * wl[j * 512 + k + e];
        }
    }
    float* orow = out + ((size_t)b * 60 + s) * 14;
#pragma unroll
    for (int j = 0; j < 6; ++j) orow[j] = acc[j];
}

// one thread per b: 8 dots over the 1024-wide concat row, broadcast to 60 slots
__global__ __launch_bounds__(256) void gout_kernel(
    const short* __restrict__ h1, const float* __restrict__ Wgp,
    const float* __restrict__ bgp, float* __restrict__ out)
{
    __shared__ float wg[8 * 1024];
    for (int i = threadIdx.x; i < 8 * 1024; i += 256) wg[i] = Wgp[i];
    __syncthreads();

    int b = blockIdx.x * 256 + threadIdx.x;
    if (b >= BATCH) return;
    const short* ha = h1 + (size_t)b * 512;                 // t = 0
    const short* hb = h1 + ((size_t)61 * BATCH + b) * 512;  // t = 61

    float acc[8];
#pragma unroll
    for (int j = 0; j < 8; ++j) acc[j] = bgp[j];
    for (int k = 0; k < 512; k += 8) {
        short8 h1v = *reinterpret_cast<const short8*>(ha + k);
        short8 h2v = *reinterpret_cast<const short8*>(hb + k);
#pragma unroll
        for (int e = 0; e < 8; ++e) {
            float v1 = bf2f(h1v[e]);
            float v2 = bf2f(h2v[e]);
#pragma unroll
            for (int j = 0; j < 8; ++j) {
                acc[j] += v1 * wg[j * 1024 + k + e];
                acc[j] += v2 * wg[j * 1024 + 512 + k + e];
            }
        }
    }
    for (int s = 0; s < 60; ++s) {
        float* orow = out + ((size_t)b * 60 + s) * 14 + 6;
#pragma unroll
        for (int j = 0; j < 8; ++j) orow[j] = acc[j];
    }
}

// ---------------- launch ---------------------------------------------------
extern "C" void kernel_launch(void* const* d_in, const int* in_sizes, int n_in,
                              void* d_out, int out_size, void* d_ws, size_t ws_size,
                              hipStream_t stream)
{
    const float* x    = (const float*)d_in[0];
    const float* Wg   = (const float*)d_in[1];
    const float* bg   = (const float*)d_in[2];
    const float* Wl   = (const float*)d_in[3];
    const float* bl   = (const float*)d_in[4];
    const float* Wih0 = (const float*)d_in[5];
    const float* Whh0 = (const float*)d_in[6];
    const float* bih0 = (const float*)d_in[7];
    const float* bhh0 = (const float*)d_in[8];
    const float* Wih1 = (const float*)d_in[9];
    const float* Whh1 = (const float*)d_in[10];
    const float* bih1 = (const float*)d_in[11];
    const float* bhh1 = (const float*)d_in[12];
    const float* Wgp  = (const float*)d_in[13];
    const float* bgp  = (const float*)d_in[14];
    const float* Wlp  = (const float*)d_in[15];
    const float* blp  = (const float*)d_in[16];
    float* out = (float*)d_out;

    const size_t seq_elems  = (size_t)TSTEPS * BATCH * 256;  // 16,252,928
    const size_t h_elems    = (size_t)TSTEPS * BATCH * 512;  // 32,505,856
    const int    wih0_elems = 2 * 1024 * 256;                // 524,288
    const int    whh0_elems = 2 * 1024 * 256;
    const int    wih1_elems = 2 * 1024 * 512;                // 1,048,576
    const int    whh1_elems = 2 * 1024 * 256;

    short* seq   = (short*)d_ws;
    short* h0    = seq + seq_elems;
    short* h1    = h0 + h_elems;
    short* wih0b = h1 + h_elems;
    short* whh0b = wih0b + wih0_elems;
    short* wih1b = whh0b + whh0_elems;
    short* whh1b = wih1b + wih1_elems;
    const size_t need = (seq_elems + 2 * h_elems +
                         wih0_elems + whh0_elems + wih1_elems + whh1_elems) * sizeof(short);
    if (ws_size < need) return;

    f2b_kernel<<<(wih0_elems + 255) / 256, 256, 0, stream>>>(Wih0, wih0b, wih0_elems);
    f2b_kernel<<<(whh0_elems + 255) / 256, 256, 0, stream>>>(Whh0, whh0b, whh0_elems);
    f2b_kernel<<<(wih1_elems + 255) / 256, 256, 0, stream>>>(Wih1, wih1b, wih1_elems);
    f2b_kernel<<<(whh1_elems + 255) / 256, 256, 0, stream>>>(Whh1, whh1b, whh1_elems);

    embed_kernel<<<BATCH, 256, 0, stream>>>(x, Wg, bg, Wl, bl, seq);
    lstm_kernel<256><<<128, 256, 0, stream>>>(seq, wih0b, whh0b, bih0, bhh0, h0);
    lstm_kernel<512><<<128, 256, 0, stream>>>(h0, wih1b, whh1b, bih1, bhh1, h1);
    lout_kernel<<<(BATCH * 60 + 255) / 256, 256, 0, stream>>>(h1, Wlp, blp, out);
    gout_kernel<<<(BATCH + 255) / 256, 256, 0, stream>>>(h1, Wgp, bgp, out);
}